// Round 1
// baseline (156.818 us; speedup 1.0000x reference)
//
#include <hip/hip_runtime.h>

#define LN_EPS 1e-5f

// ---------------------------------------------------------------------------
// ws layout (floats)
// ---------------------------------------------------------------------------
constexpr int T1_OFF   = 0;                       // 64*128*128 = 1048576 (raw s1 ReLU)
constexpr int WT2_OFF  = 1048576;                 // 25*4096 [k][pos]
constexpr int WT3_OFF  = WT2_OFF + 102400;        // 25*4096
constexpr int WT4_OFF  = WT3_OFF + 102400;        // 9*1024
constexpr int WT5_OFF  = WT4_OFF + 9216;          // 9*1024
constexpr int WT6_OFF  = WT5_OFF + 9216;          // 9*256
constexpr int FCWT_OFF = WT6_OFF + 2304;          // [kq][row][4] = 262144 floats
constexpr int R2_OFF   = FCWT_OFF + 262144;       // raw s2 ReLU [64][64][64]
constexpr int R3_OFF   = R2_OFF + 262144;         // raw s3 ReLU [64][64][64]
constexpr int R4_OFF   = R3_OFF + 262144;         // raw s4 ReLU [64][32][32]
constexpr int R5_OFF   = R4_OFF + 65536;          // raw s5 ReLU [64][32][32]
constexpr int ST1_OFF  = R5_OFF + 65536;          // [64][256][2] stage1 tile partials
constexpr int ST2_OFF  = ST1_OFF + 32768;         // [64][8][2]
constexpr int ST3_OFF  = ST2_OFF + 1024;          // [64][8][2]
constexpr int ST4_OFF  = ST3_OFF + 1024;          // [64][4][2]
constexpr int ST5_OFF  = ST4_OFF + 512;           // [64][4][2]

constexpr int NREP = 136;   // repack blocks prepended to the s1 grid

// ---------------------------------------------------------------------------
// K1: blocks [0,NREP): repack weights. blocks [NREP,NREP+1024): stage-1 conv
//     7x7 pad 3 -> raw ReLU t1 + per-(sample,tile) LN1 partial sums.
// ---------------------------------------------------------------------------
__global__ __launch_bounds__(256) void s1_conv(const float* __restrict__ x,
                                               const float* __restrict__ w1,
                                               const float* __restrict__ b1,
                                               const float* __restrict__ w2,
                                               const float* __restrict__ w3,
                                               const float* __restrict__ w4,
                                               const float* __restrict__ w5,
                                               const float* __restrict__ w6,
                                               const float* __restrict__ fcw,
                                               float* __restrict__ ws)
{
    const int tid = threadIdx.x;

    if (blockIdx.x < NREP) {
        const int rb = blockIdx.x;
        if (rb < 32) {              // w2 -> wT2  [25][4096]
            for (int idx = rb * 256 + tid; idx < 102400; idx += 32 * 256) {
                int p = idx / 25, k = idx % 25;
                ws[WT2_OFF + k * 4096 + p] = w2[idx];
            }
        } else if (rb < 64) {       // w3 -> wT3
            for (int idx = (rb - 32) * 256 + tid; idx < 102400; idx += 32 * 256) {
                int p = idx / 25, k = idx % 25;
                ws[WT3_OFF + k * 4096 + p] = w3[idx];
            }
        } else if (rb < 68) {       // w4 -> wT4  [9][1024]
            for (int idx = (rb - 64) * 256 + tid; idx < 9216; idx += 4 * 256) {
                int p = idx / 9, k = idx % 9;
                ws[WT4_OFF + k * 1024 + p] = w4[idx];
            }
        } else if (rb < 72) {       // w5 -> wT5
            for (int idx = (rb - 68) * 256 + tid; idx < 9216; idx += 4 * 256) {
                int p = idx / 9, k = idx % 9;
                ws[WT5_OFF + k * 1024 + p] = w5[idx];
            }
        } else if (rb < 73) {       // w6 -> wT6  [9][256]
            for (int idx = tid; idx < 2304; idx += 256) {
                int p = idx / 9, k = idx % 9;
                ws[WT6_OFF + k * 256 + p] = w6[idx];
            }
        } else {                    // fcw [1024,256] -> fcwT4 [kq][row][4]
            for (int idx = (rb - 73) * 256 + tid; idx < 262144; idx += 63 * 256) {
                int r = idx >> 8, kc = idx & 255;
                int kq = kc >> 2, c = kc & 3;
                ws[FCWT_OFF + kq * 4096 + r * 4 + c] = fcw[idx];
            }
        }
        return;
    }

    // ---- stage-1 conv: 8x8 tile x 16 samples ----
    constexpr int R = 128, K = 7, TILE = 8, S = 16, PAD = 3;
    constexpr int RT = TILE + K - 1;
    constexpr int PP = RT * RT + 1;
    constexpr int NBLK = R / TILE;
    constexpr int WCNT = TILE * TILE * K * K;
    constexpr int PG = 256 / S;
    constexpr int OPT = TILE * TILE / PG;

    __shared__ float s_in[S * PP];
    __shared__ float s_w[WCNT];
    __shared__ float s_b[TILE * TILE];
    __shared__ float sp[4][16], sq[4][16];

    float* t1 = ws + T1_OFF;
    const int cb = blockIdx.x - NREP;
    const int bt = cb % (NBLK * NBLK);
    const int sg = cb / (NBLK * NBLK);
    const int i0 = (bt / NBLK) * TILE;
    const int j0 = (bt % NBLK) * TILE;
    const int S0 = sg * S;

    for (int idx = tid; idx < WCNT; idx += 256) {
        int pi = idx / (K * K), kk = idx % (K * K);
        int gi = i0 + pi / TILE, gj = j0 + pi % TILE;
        s_w[idx] = w1[(gi * R + gj) * (K * K) + kk];
    }
    if (tid < TILE * TILE)
        s_b[tid] = b1[(i0 + tid / TILE) * R + (j0 + tid % TILE)];

    for (int idx = tid; idx < S * RT * RT; idx += 256) {
        int ls = idx / (RT * RT), p = idx % (RT * RT);
        int ci = i0 - PAD + p / RT, cj = j0 - PAD + p % RT;
        float v = 0.0f;
        if (ci >= 0 && ci < R && cj >= 0 && cj < R)
            v = x[(S0 + ls) * R * R + ci * R + cj];
        s_in[ls * PP + p] = v;
    }
    __syncthreads();

    const int s = tid % S;
    const int pg = tid / S;
    const int p0 = pg * OPT;
    const int ti = p0 / TILE, tj0 = p0 % TILE;
    float acc[OPT];
    #pragma unroll
    for (int o = 0; o < OPT; o++) acc[o] = s_b[p0 + o];
    #pragma unroll
    for (int ki = 0; ki < K; ki++) {
        float row[OPT + K - 1];
        #pragma unroll
        for (int c = 0; c < OPT + K - 1; c++)
            row[c] = s_in[s * PP + (ti + ki) * RT + tj0 + c];
        #pragma unroll
        for (int kj = 0; kj < K; kj++)
            #pragma unroll
            for (int o = 0; o < OPT; o++)
                acc[o] += row[o + kj] * s_w[(p0 + o) * (K * K) + ki * K + kj];
    }
    float lsum = 0.f, lsq = 0.f;
    #pragma unroll
    for (int o = 0; o < OPT; o++) {
        float v = fmaxf(acc[o], 0.0f);
        t1[(S0 + s) * R * R + (i0 + ti) * R + (j0 + tj0 + o)] = v;
        lsum += v; lsq += v * v;
    }
    // reduce across the 16 threads (lanes s, s+16, s+32, s+48 per wave) per sample
    lsum += __shfl_xor(lsum, 16, 64); lsum += __shfl_xor(lsum, 32, 64);
    lsq  += __shfl_xor(lsq,  16, 64); lsq  += __shfl_xor(lsq,  32, 64);
    const int w = tid >> 6, l = tid & 63;
    if (l < 16) { sp[w][l] = lsum; sq[w][l] = lsq; }
    __syncthreads();
    if (tid < 16) {
        float a = sp[0][tid] + sp[1][tid] + sp[2][tid] + sp[3][tid];
        float b = sq[0][tid] + sq[1][tid] + sq[2][tid] + sq[3][tid];
        ws[ST1_OFF + (S0 + tid) * 512 + bt * 2]     = a;
        ws[ST1_OFF + (S0 + tid) * 512 + bt * 2 + 1] = b;
    }
}

// ---------------------------------------------------------------------------
// 256-thread block reduce: totals land in red[0] (sum) and red[4] (sumsq).
// Caller must __syncthreads() before calling a second time.
// ---------------------------------------------------------------------------
__device__ __forceinline__ void block_sum2_256(float a, float b, float* red)
{
    const int tid = threadIdx.x;
    #pragma unroll
    for (int off = 32; off > 0; off >>= 1) {
        a += __shfl_down(a, off, 64);
        b += __shfl_down(b, off, 64);
    }
    if ((tid & 63) == 0) { red[tid >> 6] = a; red[4 + (tid >> 6)] = b; }
    __syncthreads();
    if (tid == 0) {
        red[0] = red[0] + red[1] + red[2] + red[3];
        red[4] = red[4] + red[5] + red[6] + red[7];
    }
    __syncthreads();
}

// ---------------------------------------------------------------------------
// Generic LN(+pool) -> conv KxK -> ReLU stage. One block = 8 output rows of
// one sample. Reads previous raw map + its LN stat partials; writes raw
// output map + per-slab stat partials.
//   M: output resolution. POOL: input map is 2M res, pooled after LN.
// ---------------------------------------------------------------------------
template<int M, int K, bool POOL>
__global__ __launch_bounds__(256) void stage_conv(
    const float* __restrict__ wsr, float* __restrict__ wsw,
    const float* __restrict__ g, const float* __restrict__ be,
    const float* __restrict__ bias,
    int inOff, int wtOff, int outOff,
    int stInOff, int nStatIn, float invNIn, int stOutOff)
{
    constexpr int NSLAB  = M / 8;
    constexpr int PADK   = (K - 1) / 2;
    constexpr int HR     = 8 + 2 * PADK;           // input slab rows
    constexpr int IN_RES = POOL ? 2 * M : M;
    constexpr int STR    = M + 1;

    __shared__ float Isl[HR * STR];
    __shared__ float red[8];

    const int tid  = threadIdx.x;
    const int s    = blockIdx.x / NSLAB;
    const int slab = blockIdx.x % NSLAB;
    const int r0   = slab * 8;

    // reduce input-LN stat partials (redundant per block; tiny)
    float a = 0.f, b = 0.f;
    for (int t = tid; t < nStatIn; t += 256) {
        a += wsr[stInOff + (s * nStatIn + t) * 2];
        b += wsr[stInOff + (s * nStatIn + t) * 2 + 1];
    }
    block_sum2_256(a, b, red);
    const float mu = red[0] * invNIn;
    const float rs = rsqrtf(red[4] * invNIn - mu * mu + LN_EPS);

    const float* In = wsr + inOff + s * (IN_RES * IN_RES);

    // build LN(+pool) input slab rows [r0-PADK, r0+8+PADK)
    for (int idx = tid; idx < HR * M; idx += 256) {
        int lr = idx / M, jc = idx % M;
        int gr = r0 - PADK + lr;
        float v = 0.f;
        if (gr >= 0 && gr < M) {
            if constexpr (POOL) {
                float2 xa = *(const float2*)(In + (2 * gr) * IN_RES + 2 * jc);
                float2 xb = *(const float2*)(In + (2 * gr + 1) * IN_RES + 2 * jc);
                float2 ga = *(const float2*)(g  + (2 * gr) * IN_RES + 2 * jc);
                float2 gb = *(const float2*)(g  + (2 * gr + 1) * IN_RES + 2 * jc);
                float2 ea = *(const float2*)(be + (2 * gr) * IN_RES + 2 * jc);
                float2 eb = *(const float2*)(be + (2 * gr + 1) * IN_RES + 2 * jc);
                float n0 = (xa.x - mu) * rs * ga.x + ea.x;
                float n1 = (xa.y - mu) * rs * ga.y + ea.y;
                float n2 = (xb.x - mu) * rs * gb.x + eb.x;
                float n3 = (xb.y - mu) * rs * gb.y + eb.y;
                v = fmaxf(fmaxf(n0, n1), fmaxf(n2, n3));
            } else {
                int q = gr * M + jc;
                v = (In[q] - mu) * rs * g[q] + be[q];
            }
        }
        Isl[lr * STR + jc] = v;
    }
    __syncthreads();

    const float* wT = wsr + wtOff;
    constexpr int OPW = (8 * M) / 256;     // M=64 -> 2, M=32 -> 1
    float lsum = 0.f, lsq = 0.f;
    #pragma unroll
    for (int o = 0; o < OPW; o++) {
        int p  = tid + o * 256;
        int li = p / M, j = p % M;
        int gi = r0 + li;
        int gp = gi * M + j;
        float acc = bias[gp];
        #pragma unroll
        for (int ki = 0; ki < K; ki++)
            #pragma unroll
            for (int kj = 0; kj < K; kj++) {
                int jj = j - PADK + kj;
                float iv = (jj >= 0 && jj < M) ? Isl[(li + ki) * STR + jj] : 0.f;
                acc += iv * wT[(ki * K + kj) * (M * M) + gp];
            }
        float v = fmaxf(acc, 0.f);
        wsw[outOff + s * (M * M) + gp] = v;
        lsum += v; lsq += v * v;
    }
    __syncthreads();
    block_sum2_256(lsum, lsq, red);
    if (tid == 0) {
        wsw[stOutOff + (s * NSLAB + slab) * 2]     = red[0];
        wsw[stOutOff + (s * NSLAB + slab) * 2 + 1] = red[4];
    }
}

// ---------------------------------------------------------------------------
// K6: LN5+pool -> conv3 (16x16) -> LN6 -> FC -> softmax. One block/sample.
// ---------------------------------------------------------------------------
constexpr int NT = 1024;
constexpr int NW = NT / 64;

__device__ __forceinline__ void stats_reduce(float* red, float lsum, float lsq,
                                             float inv_n, float* s_mu, float* s_rs)
{
    const int tid = threadIdx.x;
    #pragma unroll
    for (int off = 32; off > 0; off >>= 1) {
        lsum += __shfl_down(lsum, off, 64);
        lsq  += __shfl_down(lsq,  off, 64);
    }
    if ((tid & 63) == 0) { red[tid >> 6] = lsum; red[NW + (tid >> 6)] = lsq; }
    __syncthreads();
    if (tid == 0) {
        float a = 0.f, b = 0.f;
        #pragma unroll
        for (int i = 0; i < NW; i++) { a += red[i]; b += red[NW + i]; }
        float mu = a * inv_n, ms = b * inv_n;
        *s_mu = mu;
        *s_rs = rsqrtf(ms - mu * mu + LN_EPS);
    }
    __syncthreads();
}

__global__ __launch_bounds__(1024) void s6_tail(
    const float* __restrict__ wsr,
    const float* __restrict__ g5, const float* __restrict__ be5,
    const float* __restrict__ b6,
    const float* __restrict__ g6, const float* __restrict__ be6,
    const float* __restrict__ fcb,
    float* __restrict__ outp)
{
    __shared__ float I6[16 * 17];
    __shared__ float h[256];
    __shared__ float red[2 * NW];
    __shared__ float s_mu, s_rs;

    const int s = blockIdx.x;
    const int tid = threadIdx.x;

    // LN5 stats from K5 partials
    if (tid == 0) {
        float a = 0.f, b = 0.f;
        #pragma unroll
        for (int i = 0; i < 4; i++) {
            a += wsr[ST5_OFF + (s * 4 + i) * 2];
            b += wsr[ST5_OFF + (s * 4 + i) * 2 + 1];
        }
        float mu = a * (1.f / 1024.f);
        s_mu = mu;
        s_rs = rsqrtf(b * (1.f / 1024.f) - mu * mu + LN_EPS);
    }
    __syncthreads();
    const float mu5 = s_mu, rs5 = s_rs;
    const float* R5 = wsr + R5_OFF + s * 1024;

    // I6 = pool(LN5(R5))  (16x16, stride 17)
    if (tid < 256) {
        int i = tid >> 4, j = tid & 15;
        float2 xa = *(const float2*)(R5 + (2 * i) * 32 + 2 * j);
        float2 xb = *(const float2*)(R5 + (2 * i + 1) * 32 + 2 * j);
        float2 ga = *(const float2*)(g5 + (2 * i) * 32 + 2 * j);
        float2 gb = *(const float2*)(g5 + (2 * i + 1) * 32 + 2 * j);
        float2 ea = *(const float2*)(be5 + (2 * i) * 32 + 2 * j);
        float2 eb = *(const float2*)(be5 + (2 * i + 1) * 32 + 2 * j);
        float n0 = (xa.x - mu5) * rs5 * ga.x + ea.x;
        float n1 = (xa.y - mu5) * rs5 * ga.y + ea.y;
        float n2 = (xb.x - mu5) * rs5 * gb.x + eb.x;
        float n3 = (xb.y - mu5) * rs5 * gb.y + eb.y;
        I6[i * 17 + j] = fmaxf(fmaxf(n0, n1), fmaxf(n2, n3));
    }
    __syncthreads();

    // conv3 16x16 -> raw v, LN6 stats
    float v = 0.f, ls = 0.f, lq = 0.f;
    if (tid < 256) {
        int i = tid >> 4, j = tid & 15;
        const float* wT6 = wsr + WT6_OFF;
        float acc = b6[tid];
        #pragma unroll
        for (int ki = 0; ki < 3; ki++) {
            int ii = i - 1 + ki;
            bool rok = (ii >= 0 && ii < 16);
            #pragma unroll
            for (int kj = 0; kj < 3; kj++) {
                int jj = j - 1 + kj;
                float iv = (rok && jj >= 0 && jj < 16) ? I6[ii * 17 + jj] : 0.f;
                acc += iv * wT6[(ki * 3 + kj) * 256 + tid];
            }
        }
        v = fmaxf(acc, 0.f);
        ls = v; lq = v * v;
    }
    stats_reduce(red, ls, lq, 1.f / 256.f, &s_mu, &s_rs);
    if (tid < 256) h[tid] = (v - s_mu) * s_rs * g6[tid] + be6[tid];
    __syncthreads();

    // FC 256->1024: one logit/thread, 64 coalesced float4 weight loads.
    float acc = fcb[tid];
    {
        const float4* wq = (const float4*)(wsr + FCWT_OFF);
        const float4* h4 = (const float4*)h;
        #pragma unroll 8
        for (int kq = 0; kq < 64; kq++) {
            float4 wv = wq[kq * 1024 + tid];
            float4 hv = h4[kq];
            acc += wv.x * hv.x + wv.y * hv.y + wv.z * hv.z + wv.w * hv.w;
        }
    }

    // softmax over the block's 1024 logits
    float m = acc;
    #pragma unroll
    for (int off = 32; off > 0; off >>= 1)
        m = fmaxf(m, __shfl_down(m, off, 64));
    if ((tid & 63) == 0) red[tid >> 6] = m;
    __syncthreads();
    if (tid == 0) {
        float mm = red[0];
        #pragma unroll
        for (int i = 1; i < NW; i++) mm = fmaxf(mm, red[i]);
        s_mu = mm;
    }
    __syncthreads();
    float e = expf(acc - s_mu);
    float sum = e;
    #pragma unroll
    for (int off = 32; off > 0; off >>= 1)
        sum += __shfl_down(sum, off, 64);
    if ((tid & 63) == 0) red[NW + (tid >> 6)] = sum;
    __syncthreads();
    if (tid == 0) {
        float ss = 0.f;
        #pragma unroll
        for (int i = 0; i < NW; i++) ss += red[NW + i];
        s_rs = 1.0f / ss;
    }
    __syncthreads();
    outp[s * 1024 + tid] = e * s_rs;
}

// ---------------------------------------------------------------------------
extern "C" void kernel_launch(void* const* d_in, const int* in_sizes, int n_in,
                              void* d_out, int out_size, void* d_ws, size_t ws_size,
                              hipStream_t stream) {
    (void)in_sizes; (void)n_in; (void)out_size; (void)ws_size;

    const float* x   = (const float*)d_in[0];
    const float* w1  = (const float*)d_in[1];  const float* b1  = (const float*)d_in[2];
    const float* g1  = (const float*)d_in[3];  const float* be1 = (const float*)d_in[4];
    const float* w2  = (const float*)d_in[5];  const float* b2  = (const float*)d_in[6];
    const float* g2  = (const float*)d_in[7];  const float* be2 = (const float*)d_in[8];
    const float* w3  = (const float*)d_in[9];  const float* b3  = (const float*)d_in[10];
    const float* g3  = (const float*)d_in[11]; const float* be3 = (const float*)d_in[12];
    const float* w4  = (const float*)d_in[13]; const float* b4  = (const float*)d_in[14];
    const float* g4  = (const float*)d_in[15]; const float* be4 = (const float*)d_in[16];
    const float* w5  = (const float*)d_in[17]; const float* b5  = (const float*)d_in[18];
    const float* g5  = (const float*)d_in[19]; const float* be5 = (const float*)d_in[20];
    const float* w6  = (const float*)d_in[21]; const float* b6  = (const float*)d_in[22];
    const float* g6  = (const float*)d_in[23]; const float* be6 = (const float*)d_in[24];
    const float* fcw = (const float*)d_in[25]; const float* fcb = (const float*)d_in[26];

    float* ws = (float*)d_ws;

    s1_conv<<<NREP + 1024, 256, 0, stream>>>(x, w1, b1, w2, w3, w4, w5, w6, fcw, ws);

    // stage 2: pool(LN1(t1)) -> conv5 -> R2      (512 blocks)
    stage_conv<64, 5, true ><<<512, 256, 0, stream>>>(ws, ws, g1, be1, b2,
        T1_OFF, WT2_OFF, R2_OFF, ST1_OFF, 256, 1.f / 16384.f, ST2_OFF);
    // stage 3: LN2(R2) -> conv5 -> R3            (512 blocks)
    stage_conv<64, 5, false><<<512, 256, 0, stream>>>(ws, ws, g2, be2, b3,
        R2_OFF, WT3_OFF, R3_OFF, ST2_OFF, 8, 1.f / 4096.f, ST3_OFF);
    // stage 4: pool(LN3(R3)) -> conv3 -> R4      (256 blocks)
    stage_conv<32, 3, true ><<<256, 256, 0, stream>>>(ws, ws, g3, be3, b4,
        R3_OFF, WT4_OFF, R4_OFF, ST3_OFF, 8, 1.f / 4096.f, ST4_OFF);
    // stage 5: LN4(R4) -> conv3 -> R5            (256 blocks)
    stage_conv<32, 3, false><<<256, 256, 0, stream>>>(ws, ws, g4, be4, b5,
        R4_OFF, WT5_OFF, R5_OFF, ST4_OFF, 4, 1.f / 1024.f, ST5_OFF);

    s6_tail<<<64, 1024, 0, stream>>>((const float*)ws,
        g5, be5, b6, g6, be6, fcb, (float*)d_out);
}

// Round 2
// 156.185 us; speedup vs baseline: 1.0041x; 1.0041x over previous
//
#include <hip/hip_runtime.h>

#define LN_EPS 1e-5f

// ---------------------------------------------------------------------------
// ws layout (floats)
// ---------------------------------------------------------------------------
constexpr int T1_OFF   = 0;                       // 64*128*128 = 1048576 (raw s1 ReLU)
constexpr int WT2_OFF  = 1048576;                 // 25*4096 [k][pos]
constexpr int WT3_OFF  = WT2_OFF + 102400;        // 25*4096
constexpr int WT4_OFF  = WT3_OFF + 102400;        // 9*1024
constexpr int WT5_OFF  = WT4_OFF + 9216;          // 9*1024
constexpr int WT6_OFF  = WT5_OFF + 9216;          // 9*256
constexpr int FCWT_OFF = WT6_OFF + 2304;          // [kq][row][4] = 262144 floats
constexpr int R2_OFF   = FCWT_OFF + 262144;       // raw s2 ReLU [64][64][64]
constexpr int R3_OFF   = R2_OFF + 262144;         // raw s3 ReLU [64][64][64]
constexpr int ST1_OFF  = R3_OFF + 262144;         // [64][256][2] stage1 tile partials
constexpr int ST2_OFF  = ST1_OFF + 32768;         // [64][8][2]
constexpr int ST3_OFF  = ST2_OFF + 1024;          // [64][8][2]

constexpr int NREP = 136;   // repack blocks prepended to the s1 grid

// ---------------------------------------------------------------------------
// K1: blocks [0,NREP): repack weights. blocks [NREP,NREP+1024): stage-1 conv
//     7x7 pad 3 -> raw ReLU t1 + per-(sample,tile) LN1 partial sums.
// ---------------------------------------------------------------------------
__global__ __launch_bounds__(256) void s1_conv(const float* __restrict__ x,
                                               const float* __restrict__ w1,
                                               const float* __restrict__ b1,
                                               const float* __restrict__ w2,
                                               const float* __restrict__ w3,
                                               const float* __restrict__ w4,
                                               const float* __restrict__ w5,
                                               const float* __restrict__ w6,
                                               const float* __restrict__ fcw,
                                               float* __restrict__ ws)
{
    const int tid = threadIdx.x;

    if (blockIdx.x < NREP) {
        const int rb = blockIdx.x;
        if (rb < 32) {              // w2 -> wT2  [25][4096]
            for (int idx = rb * 256 + tid; idx < 102400; idx += 32 * 256) {
                int p = idx / 25, k = idx % 25;
                ws[WT2_OFF + k * 4096 + p] = w2[idx];
            }
        } else if (rb < 64) {       // w3 -> wT3
            for (int idx = (rb - 32) * 256 + tid; idx < 102400; idx += 32 * 256) {
                int p = idx / 25, k = idx % 25;
                ws[WT3_OFF + k * 4096 + p] = w3[idx];
            }
        } else if (rb < 68) {       // w4 -> wT4  [9][1024]
            for (int idx = (rb - 64) * 256 + tid; idx < 9216; idx += 4 * 256) {
                int p = idx / 9, k = idx % 9;
                ws[WT4_OFF + k * 1024 + p] = w4[idx];
            }
        } else if (rb < 72) {       // w5 -> wT5
            for (int idx = (rb - 68) * 256 + tid; idx < 9216; idx += 4 * 256) {
                int p = idx / 9, k = idx % 9;
                ws[WT5_OFF + k * 1024 + p] = w5[idx];
            }
        } else if (rb < 73) {       // w6 -> wT6  [9][256]
            for (int idx = tid; idx < 2304; idx += 256) {
                int p = idx / 9, k = idx % 9;
                ws[WT6_OFF + k * 256 + p] = w6[idx];
            }
        } else {                    // fcw [1024,256] -> fcwT4 [kq][row][4]
            for (int idx = (rb - 73) * 256 + tid; idx < 262144; idx += 63 * 256) {
                int r = idx >> 8, kc = idx & 255;
                int kq = kc >> 2, c = kc & 3;
                ws[FCWT_OFF + kq * 4096 + r * 4 + c] = fcw[idx];
            }
        }
        return;
    }

    // ---- stage-1 conv: 8x8 tile x 16 samples ----
    constexpr int R = 128, K = 7, TILE = 8, S = 16, PAD = 3;
    constexpr int RT = TILE + K - 1;
    constexpr int PP = RT * RT + 1;
    constexpr int NBLK = R / TILE;
    constexpr int WCNT = TILE * TILE * K * K;
    constexpr int PG = 256 / S;
    constexpr int OPT = TILE * TILE / PG;

    __shared__ float s_in[S * PP];
    __shared__ float s_w[WCNT];
    __shared__ float s_b[TILE * TILE];
    __shared__ float sp[4][16], sq[4][16];

    float* t1 = ws + T1_OFF;
    const int cb = blockIdx.x - NREP;
    const int bt = cb % (NBLK * NBLK);
    const int sg = cb / (NBLK * NBLK);
    const int i0 = (bt / NBLK) * TILE;
    const int j0 = (bt % NBLK) * TILE;
    const int S0 = sg * S;

    for (int idx = tid; idx < WCNT; idx += 256) {
        int pi = idx / (K * K), kk = idx % (K * K);
        int gi = i0 + pi / TILE, gj = j0 + pi % TILE;
        s_w[idx] = w1[(gi * R + gj) * (K * K) + kk];
    }
    if (tid < TILE * TILE)
        s_b[tid] = b1[(i0 + tid / TILE) * R + (j0 + tid % TILE)];

    for (int idx = tid; idx < S * RT * RT; idx += 256) {
        int ls = idx / (RT * RT), p = idx % (RT * RT);
        int ci = i0 - PAD + p / RT, cj = j0 - PAD + p % RT;
        float v = 0.0f;
        if (ci >= 0 && ci < R && cj >= 0 && cj < R)
            v = x[(S0 + ls) * R * R + ci * R + cj];
        s_in[ls * PP + p] = v;
    }
    __syncthreads();

    const int s = tid % S;
    const int pg = tid / S;
    const int p0 = pg * OPT;
    const int ti = p0 / TILE, tj0 = p0 % TILE;
    float acc[OPT];
    #pragma unroll
    for (int o = 0; o < OPT; o++) acc[o] = s_b[p0 + o];
    #pragma unroll
    for (int ki = 0; ki < K; ki++) {
        float row[OPT + K - 1];
        #pragma unroll
        for (int c = 0; c < OPT + K - 1; c++)
            row[c] = s_in[s * PP + (ti + ki) * RT + tj0 + c];
        #pragma unroll
        for (int kj = 0; kj < K; kj++)
            #pragma unroll
            for (int o = 0; o < OPT; o++)
                acc[o] += row[o + kj] * s_w[(p0 + o) * (K * K) + ki * K + kj];
    }
    float lsum = 0.f, lsq = 0.f;
    #pragma unroll
    for (int o = 0; o < OPT; o++) {
        float v = fmaxf(acc[o], 0.0f);
        t1[(S0 + s) * R * R + (i0 + ti) * R + (j0 + tj0 + o)] = v;
        lsum += v; lsq += v * v;
    }
    // reduce across the 16 threads (lanes s, s+16, s+32, s+48 per wave) per sample
    lsum += __shfl_xor(lsum, 16, 64); lsum += __shfl_xor(lsum, 32, 64);
    lsq  += __shfl_xor(lsq,  16, 64); lsq  += __shfl_xor(lsq,  32, 64);
    const int w = tid >> 6, l = tid & 63;
    if (l < 16) { sp[w][l] = lsum; sq[w][l] = lsq; }
    __syncthreads();
    if (tid < 16) {
        float a = sp[0][tid] + sp[1][tid] + sp[2][tid] + sp[3][tid];
        float b = sq[0][tid] + sq[1][tid] + sq[2][tid] + sq[3][tid];
        ws[ST1_OFF + (S0 + tid) * 512 + bt * 2]     = a;
        ws[ST1_OFF + (S0 + tid) * 512 + bt * 2 + 1] = b;
    }
}

// ---------------------------------------------------------------------------
// 256-thread block reduce: totals land in red[0] (sum) and red[4] (sumsq).
// ---------------------------------------------------------------------------
__device__ __forceinline__ void block_sum2_256(float a, float b, float* red)
{
    const int tid = threadIdx.x;
    #pragma unroll
    for (int off = 32; off > 0; off >>= 1) {
        a += __shfl_down(a, off, 64);
        b += __shfl_down(b, off, 64);
    }
    if ((tid & 63) == 0) { red[tid >> 6] = a; red[4 + (tid >> 6)] = b; }
    __syncthreads();
    if (tid == 0) {
        red[0] = red[0] + red[1] + red[2] + red[3];
        red[4] = red[4] + red[5] + red[6] + red[7];
    }
    __syncthreads();
}

// ---------------------------------------------------------------------------
// LN(+pool) -> conv 5x5 -> ReLU stage (64-res). One block = 8 output rows of
// one sample. Reads previous raw map + its LN stat partials; writes raw
// output map + per-slab stat partials.
// ---------------------------------------------------------------------------
template<int M, int K, bool POOL>
__global__ __launch_bounds__(256) void stage_conv(
    const float* __restrict__ wsr, float* __restrict__ wsw,
    const float* __restrict__ g, const float* __restrict__ be,
    const float* __restrict__ bias,
    int inOff, int wtOff, int outOff,
    int stInOff, int nStatIn, float invNIn, int stOutOff)
{
    constexpr int NSLAB  = M / 8;
    constexpr int PADK   = (K - 1) / 2;
    constexpr int HR     = 8 + 2 * PADK;           // input slab rows
    constexpr int IN_RES = POOL ? 2 * M : M;
    constexpr int STR    = M + 1;

    __shared__ float Isl[HR * STR];
    __shared__ float red[8];

    const int tid  = threadIdx.x;
    const int s    = blockIdx.x / NSLAB;
    const int slab = blockIdx.x % NSLAB;
    const int r0   = slab * 8;

    // reduce input-LN stat partials (redundant per block; tiny)
    float a = 0.f, b = 0.f;
    for (int t = tid; t < nStatIn; t += 256) {
        a += wsr[stInOff + (s * nStatIn + t) * 2];
        b += wsr[stInOff + (s * nStatIn + t) * 2 + 1];
    }
    block_sum2_256(a, b, red);
    const float mu = red[0] * invNIn;
    const float rs = rsqrtf(red[4] * invNIn - mu * mu + LN_EPS);

    const float* In = wsr + inOff + s * (IN_RES * IN_RES);

    // build LN(+pool) input slab rows [r0-PADK, r0+8+PADK)
    for (int idx = tid; idx < HR * M; idx += 256) {
        int lr = idx / M, jc = idx % M;
        int gr = r0 - PADK + lr;
        float v = 0.f;
        if (gr >= 0 && gr < M) {
            if constexpr (POOL) {
                float2 xa = *(const float2*)(In + (2 * gr) * IN_RES + 2 * jc);
                float2 xb = *(const float2*)(In + (2 * gr + 1) * IN_RES + 2 * jc);
                float2 ga = *(const float2*)(g  + (2 * gr) * IN_RES + 2 * jc);
                float2 gb = *(const float2*)(g  + (2 * gr + 1) * IN_RES + 2 * jc);
                float2 ea = *(const float2*)(be + (2 * gr) * IN_RES + 2 * jc);
                float2 eb = *(const float2*)(be + (2 * gr + 1) * IN_RES + 2 * jc);
                float n0 = (xa.x - mu) * rs * ga.x + ea.x;
                float n1 = (xa.y - mu) * rs * ga.y + ea.y;
                float n2 = (xb.x - mu) * rs * gb.x + eb.x;
                float n3 = (xb.y - mu) * rs * gb.y + eb.y;
                v = fmaxf(fmaxf(n0, n1), fmaxf(n2, n3));
            } else {
                int q = gr * M + jc;
                v = (In[q] - mu) * rs * g[q] + be[q];
            }
        }
        Isl[lr * STR + jc] = v;
    }
    __syncthreads();

    const float* wT = wsr + wtOff;
    constexpr int OPW = (8 * M) / 256;
    float lsum = 0.f, lsq = 0.f;
    #pragma unroll
    for (int o = 0; o < OPW; o++) {
        int p  = tid + o * 256;
        int li = p / M, j = p % M;
        int gi = r0 + li;
        int gp = gi * M + j;
        float acc = bias[gp];
        #pragma unroll
        for (int ki = 0; ki < K; ki++)
            #pragma unroll
            for (int kj = 0; kj < K; kj++) {
                int jj = j - PADK + kj;
                float iv = (jj >= 0 && jj < M) ? Isl[(li + ki) * STR + jj] : 0.f;
                acc += iv * wT[(ki * K + kj) * (M * M) + gp];
            }
        float v = fmaxf(acc, 0.f);
        wsw[outOff + s * (M * M) + gp] = v;
        lsum += v; lsq += v * v;
    }
    __syncthreads();
    block_sum2_256(lsum, lsq, red);
    if (tid == 0) {
        wsw[stOutOff + (s * NSLAB + slab) * 2]     = red[0];
        wsw[stOutOff + (s * NSLAB + slab) * 2 + 1] = red[4];
    }
}

// ---------------------------------------------------------------------------
// K4: fused tail — pool(LN3(R3)) -> conv4 -> LN4 -> conv5 -> LN5 -> pool
//     -> conv6 -> LN6 -> FC -> softmax. One 1024-thread block per sample.
// ---------------------------------------------------------------------------
constexpr int NT = 1024;
constexpr int NW = NT / 64;

__device__ __forceinline__ void stats_reduce(float* red, float lsum, float lsq,
                                             float inv_n, float* s_mu, float* s_rs)
{
    const int tid = threadIdx.x;
    #pragma unroll
    for (int off = 32; off > 0; off >>= 1) {
        lsum += __shfl_down(lsum, off, 64);
        lsq  += __shfl_down(lsq,  off, 64);
    }
    if ((tid & 63) == 0) { red[tid >> 6] = lsum; red[NW + (tid >> 6)] = lsq; }
    __syncthreads();
    if (tid == 0) {
        float a = 0.f, b = 0.f;
        #pragma unroll
        for (int i = 0; i < NW; i++) { a += red[i]; b += red[NW + i]; }
        float mu = a * inv_n, ms = b * inv_n;
        *s_mu = mu;
        *s_rs = rsqrtf(ms - mu * mu + LN_EPS);
    }
    __syncthreads();
}

__global__ __launch_bounds__(1024) void tail46(
    const float* __restrict__ wsr,
    const float* __restrict__ g3, const float* __restrict__ be3,
    const float* __restrict__ b4,
    const float* __restrict__ g4, const float* __restrict__ be4,
    const float* __restrict__ b5,
    const float* __restrict__ g5, const float* __restrict__ be5,
    const float* __restrict__ b6,
    const float* __restrict__ g6, const float* __restrict__ be6,
    const float* __restrict__ fcb,
    float* __restrict__ outp)
{
    __shared__ float A[32 * 33];    // I4, later n5
    __shared__ float B[32 * 33];    // I5
    __shared__ float I6[16 * 17];
    __shared__ float h[256];
    __shared__ float red[2 * NW];
    __shared__ float s_mu, s_rs;

    const int s = blockIdx.x;
    const int tid = threadIdx.x;
    const int i = tid >> 5, j = tid & 31;   // 32x32 position of this thread

    // LN3 stats from stage-3 partials (8 per sample)
    if (tid == 0) {
        float a = 0.f, bq = 0.f;
        #pragma unroll
        for (int t = 0; t < 8; t++) {
            a  += wsr[ST3_OFF + (s * 8 + t) * 2];
            bq += wsr[ST3_OFF + (s * 8 + t) * 2 + 1];
        }
        float mu = a * (1.f / 4096.f);
        s_mu = mu;
        s_rs = rsqrtf(bq * (1.f / 4096.f) - mu * mu + LN_EPS);
    }
    __syncthreads();

    // I4 = pool(LN3(R3))  32x32 stride 33
    {
        const float mu = s_mu, rs = s_rs;
        const float* R3 = wsr + R3_OFF + s * 4096;
        float2 xa = *(const float2*)(R3  + (2 * i) * 64 + 2 * j);
        float2 xb = *(const float2*)(R3  + (2 * i + 1) * 64 + 2 * j);
        float2 ga = *(const float2*)(g3  + (2 * i) * 64 + 2 * j);
        float2 gb = *(const float2*)(g3  + (2 * i + 1) * 64 + 2 * j);
        float2 ea = *(const float2*)(be3 + (2 * i) * 64 + 2 * j);
        float2 eb = *(const float2*)(be3 + (2 * i + 1) * 64 + 2 * j);
        float n0 = (xa.x - mu) * rs * ga.x + ea.x;
        float n1 = (xa.y - mu) * rs * ga.y + ea.y;
        float n2 = (xb.x - mu) * rs * gb.x + eb.x;
        float n3 = (xb.y - mu) * rs * gb.y + eb.y;
        A[i * 33 + j] = fmaxf(fmaxf(n0, n1), fmaxf(n2, n3));
    }
    __syncthreads();

    const float* wT4 = wsr + WT4_OFF;
    const float* wT5 = wsr + WT5_OFF;
    const float* wT6 = wsr + WT6_OFF;

    // conv4 3x3 on A -> v4, LN4 -> B
    float v4;
    {
        float acc = b4[tid];
        #pragma unroll
        for (int ki = 0; ki < 3; ki++) {
            int ii = i - 1 + ki;
            bool rok = (ii >= 0 && ii < 32);
            #pragma unroll
            for (int kj = 0; kj < 3; kj++) {
                int jj = j - 1 + kj;
                float iv = (rok && jj >= 0 && jj < 32) ? A[ii * 33 + jj] : 0.f;
                acc += iv * wT4[(ki * 3 + kj) * 1024 + tid];
            }
        }
        v4 = fmaxf(acc, 0.f);
    }
    stats_reduce(red, v4, v4 * v4, 1.f / 1024.f, &s_mu, &s_rs);
    B[i * 33 + j] = (v4 - s_mu) * s_rs * g4[tid] + be4[tid];
    __syncthreads();

    // conv5 3x3 on B -> v5, LN5 -> A (n5 at 32-res)
    float v5;
    {
        float acc = b5[tid];
        #pragma unroll
        for (int ki = 0; ki < 3; ki++) {
            int ii = i - 1 + ki;
            bool rok = (ii >= 0 && ii < 32);
            #pragma unroll
            for (int kj = 0; kj < 3; kj++) {
                int jj = j - 1 + kj;
                float iv = (rok && jj >= 0 && jj < 32) ? B[ii * 33 + jj] : 0.f;
                acc += iv * wT5[(ki * 3 + kj) * 1024 + tid];
            }
        }
        v5 = fmaxf(acc, 0.f);
    }
    stats_reduce(red, v5, v5 * v5, 1.f / 1024.f, &s_mu, &s_rs);
    A[i * 33 + j] = (v5 - s_mu) * s_rs * g5[tid] + be5[tid];
    __syncthreads();

    // pool n5 -> I6 (16x16 stride 17)
    if (tid < 256) {
        int ii = tid >> 4, jj = tid & 15;
        float p0 = A[(2 * ii) * 33 + 2 * jj],     p1 = A[(2 * ii) * 33 + 2 * jj + 1];
        float p2 = A[(2 * ii + 1) * 33 + 2 * jj], p3 = A[(2 * ii + 1) * 33 + 2 * jj + 1];
        I6[ii * 17 + jj] = fmaxf(fmaxf(p0, p1), fmaxf(p2, p3));
    }
    __syncthreads();

    // conv6 3x3 on I6 -> v6, LN6 stats
    float v6 = 0.f, ls = 0.f, lq = 0.f;
    if (tid < 256) {
        int ii = tid >> 4, jj = tid & 15;
        float acc = b6[tid];
        #pragma unroll
        for (int ki = 0; ki < 3; ki++) {
            int ri = ii - 1 + ki;
            bool rok = (ri >= 0 && ri < 16);
            #pragma unroll
            for (int kj = 0; kj < 3; kj++) {
                int cj = jj - 1 + kj;
                float iv = (rok && cj >= 0 && cj < 16) ? I6[ri * 17 + cj] : 0.f;
                acc += iv * wT6[(ki * 3 + kj) * 256 + tid];
            }
        }
        v6 = fmaxf(acc, 0.f);
        ls = v6; lq = v6 * v6;
    }
    stats_reduce(red, ls, lq, 1.f / 256.f, &s_mu, &s_rs);
    if (tid < 256) h[tid] = (v6 - s_mu) * s_rs * g6[tid] + be6[tid];
    __syncthreads();

    // FC 256->1024: one logit/thread, 64 coalesced float4 weight loads.
    float acc = fcb[tid];
    {
        const float4* wq = (const float4*)(wsr + FCWT_OFF);
        const float4* h4 = (const float4*)h;
        #pragma unroll 8
        for (int kq = 0; kq < 64; kq++) {
            float4 wv = wq[kq * 1024 + tid];
            float4 hv = h4[kq];
            acc += wv.x * hv.x + wv.y * hv.y + wv.z * hv.z + wv.w * hv.w;
        }
    }

    // softmax over the block's 1024 logits
    float m = acc;
    #pragma unroll
    for (int off = 32; off > 0; off >>= 1)
        m = fmaxf(m, __shfl_down(m, off, 64));
    if ((tid & 63) == 0) red[tid >> 6] = m;
    __syncthreads();
    if (tid == 0) {
        float mm = red[0];
        #pragma unroll
        for (int t = 1; t < NW; t++) mm = fmaxf(mm, red[t]);
        s_mu = mm;
    }
    __syncthreads();
    float e = expf(acc - s_mu);
    float sum = e;
    #pragma unroll
    for (int off = 32; off > 0; off >>= 1)
        sum += __shfl_down(sum, off, 64);
    if ((tid & 63) == 0) red[NW + (tid >> 6)] = sum;
    __syncthreads();
    if (tid == 0) {
        float ss = 0.f;
        #pragma unroll
        for (int t = 0; t < NW; t++) ss += red[NW + t];
        s_rs = 1.0f / ss;
    }
    __syncthreads();
    outp[s * 1024 + tid] = e * s_rs;
}

// ---------------------------------------------------------------------------
extern "C" void kernel_launch(void* const* d_in, const int* in_sizes, int n_in,
                              void* d_out, int out_size, void* d_ws, size_t ws_size,
                              hipStream_t stream) {
    (void)in_sizes; (void)n_in; (void)out_size; (void)ws_size;

    const float* x   = (const float*)d_in[0];
    const float* w1  = (const float*)d_in[1];  const float* b1  = (const float*)d_in[2];
    const float* g1  = (const float*)d_in[3];  const float* be1 = (const float*)d_in[4];
    const float* w2  = (const float*)d_in[5];  const float* b2  = (const float*)d_in[6];
    const float* g2  = (const float*)d_in[7];  const float* be2 = (const float*)d_in[8];
    const float* w3  = (const float*)d_in[9];  const float* b3  = (const float*)d_in[10];
    const float* g3  = (const float*)d_in[11]; const float* be3 = (const float*)d_in[12];
    const float* w4  = (const float*)d_in[13]; const float* b4  = (const float*)d_in[14];
    const float* g4  = (const float*)d_in[15]; const float* be4 = (const float*)d_in[16];
    const float* w5  = (const float*)d_in[17]; const float* b5  = (const float*)d_in[18];
    const float* g5  = (const float*)d_in[19]; const float* be5 = (const float*)d_in[20];
    const float* w6  = (const float*)d_in[21]; const float* b6  = (const float*)d_in[22];
    const float* g6  = (const float*)d_in[23]; const float* be6 = (const float*)d_in[24];
    const float* fcw = (const float*)d_in[25]; const float* fcb = (const float*)d_in[26];

    float* ws = (float*)d_ws;

    s1_conv<<<NREP + 1024, 256, 0, stream>>>(x, w1, b1, w2, w3, w4, w5, w6, fcw, ws);

    // stage 2: pool(LN1(t1)) -> conv5 -> R2      (512 blocks)
    stage_conv<64, 5, true ><<<512, 256, 0, stream>>>(ws, ws, g1, be1, b2,
        T1_OFF, WT2_OFF, R2_OFF, ST1_OFF, 256, 1.f / 16384.f, ST2_OFF);
    // stage 3: LN2(R2) -> conv5 -> R3            (512 blocks)
    stage_conv<64, 5, false><<<512, 256, 0, stream>>>(ws, ws, g2, be2, b3,
        R2_OFF, WT3_OFF, R3_OFF, ST2_OFF, 8, 1.f / 4096.f, ST3_OFF);

    // fused stages 4-6 + FC + softmax (64 blocks x 1024 thr)
    tail46<<<64, 1024, 0, stream>>>((const float*)ws,
        g3, be3, b4, g4, be4, b5, g5, be5, b6, g6, be6,
        fcb, (float*)d_out);
}